// Round 1
// baseline (8625.052 us; speedup 1.0000x reference)
//
#include <hip/hip_runtime.h>
#include <cstdint>
#include <cstddef>

#define BS 256
#define SEQ 4096
#define D 128
#define NC 256   // num categories
#define TD 384   // 3*D

// ---------------------------------------------------------------------------
// Kernel A: proj[tok][c] = embed_table[tok,:] @ Wi[:,c] + bi[c]
// proj has 257 rows (row NC is the BOS embedding projection).
// Tiny: 257*384 outputs, 128 MACs each.
// ---------------------------------------------------------------------------
__global__ __launch_bounds__(384) void proj_kernel(
    const float* __restrict__ embed, const float* __restrict__ Wi,
    const float* __restrict__ bi, float* __restrict__ proj)
{
    const int row = blockIdx.x;   // 0..256
    const int j   = threadIdx.x;  // 0..383
    __shared__ __align__(16) float e[D];
    if (j < D) e[j] = embed[row * D + j];
    __syncthreads();
    float acc = bi[j];
#pragma unroll
    for (int k = 0; k < D; ++k) acc += e[k] * Wi[k * TD + j];
    proj[row * TD + j] = acc;
}

// ---------------------------------------------------------------------------
// Kernel B: the GRU recurrence + logits. One workgroup per batch row.
// block = 256 threads (4 waves). Thread j owns:
//   - column j of Wh_rz (j<128 -> hr column, j>=128 -> hz column)   [128 regs]
//   - column j of W_cls                                              [128 regs]
//   - half of column (j mod 128) of Wh_n:
//       j<128: rows 0..63,   j>=128: rows 64..127                    [ 64 regs]
// h state is broadcast via double-buffered LDS (float4 broadcast reads).
// Tokens for the whole row staged to LDS once. xi gather prefetched 1 step.
// ---------------------------------------------------------------------------
__global__ __launch_bounds__(256, 1) void gru_kernel(
    const int*   __restrict__ x,
    const float* __restrict__ proj,
    const float* __restrict__ Wh_rz,
    const float* __restrict__ Wh_n,
    const float* __restrict__ bh_n,
    const float* __restrict__ W_cls,
    const float* __restrict__ b_cls,
    const float* __restrict__ init_state,
    float*       __restrict__ out)
{
    const int b  = blockIdx.x;     // batch row
    const int j  = threadIdx.x;    // 0..255
    const bool lo = (j < D);       // waves 0,1: r/n side; waves 2,3: z side

    __shared__ __align__(16) float hbuf[2][D];
    __shared__ float hnb[D];
    __shared__ float zbuf[D];
    __shared__ int   toks[SEQ];

    // Stage the (shifted) token stream: toks[t] = input token at step t.
    for (int i = j; i < SEQ; i += 256) {
        toks[i] = (i == 0) ? NC : x[(size_t)b * SEQ + i - 1];
    }

    // ---- load weights into registers (coalesced column loads) ----
    float wrz[D];
#pragma unroll
    for (int k = 0; k < D; ++k) wrz[k] = Wh_rz[k * 256 + j];
    float wcl[D];
#pragma unroll
    for (int k = 0; k < D; ++k) wcl[k] = W_cls[k * 256 + j];
    float wn[64];
    {
        const int col = lo ? j : (j - D);
        const int k0  = lo ? 0 : 64;
#pragma unroll
        for (int k = 0; k < 64; ++k) wn[k] = Wh_n[(k0 + k) * D + col];
    }

    float hj = 0.f, bhn_j = 0.f;
    const float bcls_j = b_cls[j];
    if (lo) { hj = init_state[j]; bhn_j = bh_n[j]; }
    if (j < D) hbuf[0][j] = init_state[j];
    __syncthreads();

    // ---- software-pipelined xi gather: values for step 0 ----
    int tok = toks[0];
    float xv = proj[tok * TD + j];                       // xr (lo) / xz (hi)
    float xn = lo ? proj[tok * TD + 2 * D + j] : 0.f;    // xn (lo only)

    for (int t = 0; t < SEQ; ++t) {
        const int cur = t & 1;
        const int nxt = cur ^ 1;

        // prefetch xi for step t+1 (token stream is input-independent)
        const int tnext = (t + 1 < SEQ) ? (t + 1) : t;
        const int tok2 = toks[tnext];
        const float xv_n = proj[tok2 * TD + j];
        const float xn_n = lo ? proj[tok2 * TD + 2 * D + j] : 0.f;

        // ---- matvecs: hr/hz column + half of hn column ----
        float a0 = 0.f, a1 = 0.f, a2 = 0.f, a3 = 0.f;
        float n0 = 0.f, n1 = 0.f;
        const float4* __restrict__ h4 = (const float4*)hbuf[cur];
        if (lo) {
#pragma unroll
            for (int kk = 0; kk < 16; ++kk) {      // k = 0..63: rz + n
                const float4 h = h4[kk];
                a0 += h.x * wrz[4*kk+0]; a1 += h.y * wrz[4*kk+1];
                a2 += h.z * wrz[4*kk+2]; a3 += h.w * wrz[4*kk+3];
                n0 += h.x * wn[4*kk+0];  n1 += h.y * wn[4*kk+1];
                n0 += h.z * wn[4*kk+2];  n1 += h.w * wn[4*kk+3];
            }
#pragma unroll
            for (int kk = 16; kk < 32; ++kk) {     // k = 64..127: rz only
                const float4 h = h4[kk];
                a0 += h.x * wrz[4*kk+0]; a1 += h.y * wrz[4*kk+1];
                a2 += h.z * wrz[4*kk+2]; a3 += h.w * wrz[4*kk+3];
            }
        } else {
#pragma unroll
            for (int kk = 0; kk < 16; ++kk) {      // k = 0..63: rz only
                const float4 h = h4[kk];
                a0 += h.x * wrz[4*kk+0]; a1 += h.y * wrz[4*kk+1];
                a2 += h.z * wrz[4*kk+2]; a3 += h.w * wrz[4*kk+3];
            }
#pragma unroll
            for (int kk = 16; kk < 32; ++kk) {     // k = 64..127: rz + n
                const float4 h = h4[kk];
                const int m = 4*kk - 64;
                a0 += h.x * wrz[4*kk+0]; a1 += h.y * wrz[4*kk+1];
                a2 += h.z * wrz[4*kk+2]; a3 += h.w * wrz[4*kk+3];
                n0 += h.x * wn[m+0];     n1 += h.y * wn[m+1];
                n0 += h.z * wn[m+2];     n1 += h.w * wn[m+3];
            }
        }
        const float arz = (a0 + a1) + (a2 + a3);

        if (!lo) {
            // z gate on the hi half; publish z and the hn partial
            const float z = 1.f / (1.f + __expf(-(xv + arz)));
            zbuf[j - D] = z;
            hnb[j - D]  = n0 + n1;
        }
        __syncthreads();

        if (lo) {
            const float r  = 1.f / (1.f + __expf(-(xv + arz)));
            const float hn = (n0 + n1) + hnb[j] + bhn_j;
            const float pre = xn + r * hn;
            // tanh(x) = 1 - 2/(exp(2x)+1)  (saturates correctly at +-inf)
            const float nn = 1.f - 2.f / (__expf(2.f * pre) + 1.f);
            const float z  = zbuf[j];
            const float hnew = (1.f - z) * nn + z * hj;
            hj = hnew;
            hbuf[nxt][j] = hnew;
        }
        __syncthreads();

        // ---- logits: h_new @ W_cls[:, j] + b_cls[j] ----
        float c0 = 0.f, c1 = 0.f, c2 = 0.f, c3 = 0.f;
        const float4* __restrict__ g4 = (const float4*)hbuf[nxt];
#pragma unroll
        for (int kk = 0; kk < 32; ++kk) {
            const float4 h = g4[kk];
            c0 += h.x * wcl[4*kk+0]; c1 += h.y * wcl[4*kk+1];
            c2 += h.z * wcl[4*kk+2]; c3 += h.w * wcl[4*kk+3];
        }
        out[((size_t)b * SEQ + t) * NC + j] = ((c0 + c1) + (c2 + c3)) + bcls_j;

        xv = xv_n; xn = xn_n;
    }
}

// ---------------------------------------------------------------------------
extern "C" void kernel_launch(void* const* d_in, const int* in_sizes, int n_in,
                              void* d_out, int out_size, void* d_ws, size_t ws_size,
                              hipStream_t stream)
{
    const int*   x          = (const int*)  d_in[0];
    const float* embed      = (const float*)d_in[1];
    const float* Wi         = (const float*)d_in[2];
    const float* bi         = (const float*)d_in[3];
    const float* Wh_rz      = (const float*)d_in[4];
    const float* Wh_n       = (const float*)d_in[5];
    const float* bh_n       = (const float*)d_in[6];
    const float* W_cls      = (const float*)d_in[7];
    const float* b_cls      = (const float*)d_in[8];
    const float* init_state = (const float*)d_in[9];
    float* out  = (float*)d_out;
    float* proj = (float*)d_ws;   // (NC+1) x 3D = 257*384 floats = 395 KB

    proj_kernel<<<dim3(NC + 1), dim3(TD), 0, stream>>>(embed, Wi, bi, proj);
    gru_kernel<<<dim3(BS), dim3(256), 0, stream>>>(
        x, proj, Wh_rz, Wh_n, bh_n, W_cls, b_cls, init_state, out);
}